// Round 2
// baseline (214.157 us; speedup 1.0000x reference)
//
#include <hip/hip_runtime.h>
#include <hip/hip_bf16.h>
#include <stdint.h>

// LoRAExpert: out = ragged_dot(x, W, groups) + scale[a] * ((x @ A[a,e]) @ B[a,e])
// T=8192, D_IN=D_OUT=1024, E=8 (equal groups of 1024), A=4 adapters, R=16.
// Dtype theory (round 2): inputs fp32 (per reference), output fp32.
// Compute: convert to bf16 in staging, MFMA bf16, accumulate fp32. 2% rel
// threshold >> bf16 accumulation noise (~4e-3).

#define T_TOK 8192
#define DIN   1024
#define DOUT  1024
#define NE    8
#define NA    4
#define RK    16

typedef __attribute__((ext_vector_type(8))) short short8;
typedef __attribute__((ext_vector_type(4))) float f32x4;

__device__ __forceinline__ ushort f2bf(float f) {
  union { float f; uint32_t i; } v; v.f = f;
  uint32_t x = v.i;
  return (ushort)((x + 0x7fffu + ((x >> 16) & 1u)) >> 16);  // RNE
}

// ---- kernel 1: token -> expert map (from group_sizes prefix) ----
__global__ void k_token_expert(const int* __restrict__ gs, int* __restrict__ tok_exp) {
  int t = blockIdx.x * blockDim.x + threadIdx.x;
  if (t >= T_TOK) return;
  int cum = 0, e = 0;
#pragma unroll
  for (int i = 0; i < NE; ++i) { if (t >= cum) e = i; cum += gs[i]; }
  tok_exp[t] = e;
}

// ---- kernel 2: V'[t, 64] = adapter-slotted scale*(x@A[a,e]), fp32, zero elsewhere ----
__global__ __launch_bounds__(256) void k_vprime(
    const float* __restrict__ x, const float* __restrict__ lora_A,
    const float* __restrict__ lora_scaling, const int* __restrict__ adapter_idx,
    const int* __restrict__ tok_exp, float* __restrict__ vprime) {
  const int lane = threadIdx.x & 63;
  const int t = blockIdx.x * 4 + (threadIdx.x >> 6);
  const int a = adapter_idx[t];
  const int e = tok_exp[t];
  const float* abase = lora_A + (size_t)(a * NE + e) * DIN * RK;

  float acc[RK];
#pragma unroll
  for (int r = 0; r < RK; ++r) acc[r] = 0.f;

#pragma unroll
  for (int i = 0; i < DIN / 64; ++i) {
    int k = i * 64 + lane;                    // coalesced across lanes
    float xk = x[(size_t)t * DIN + k];
    const float* ar = abase + (size_t)k * RK; // 16 floats, 64B
    float4 v0 = *(const float4*)(ar + 0);
    float4 v1 = *(const float4*)(ar + 4);
    float4 v2 = *(const float4*)(ar + 8);
    float4 v3 = *(const float4*)(ar + 12);
    acc[0]  += xk * v0.x; acc[1]  += xk * v0.y; acc[2]  += xk * v0.z; acc[3]  += xk * v0.w;
    acc[4]  += xk * v1.x; acc[5]  += xk * v1.y; acc[6]  += xk * v1.z; acc[7]  += xk * v1.w;
    acc[8]  += xk * v2.x; acc[9]  += xk * v2.y; acc[10] += xk * v2.z; acc[11] += xk * v2.w;
    acc[12] += xk * v3.x; acc[13] += xk * v3.y; acc[14] += xk * v3.z; acc[15] += xk * v3.w;
  }
#pragma unroll
  for (int off = 1; off < 64; off <<= 1) {
#pragma unroll
    for (int r = 0; r < RK; ++r) acc[r] += __shfl_xor(acc[r], off, 64);
  }
  float s = lora_scaling[a];
  int c = lane;                               // output column 0..63
  vprime[(size_t)t * 64 + c] = ((c >> 4) == a) ? s * acc[c & 15] : 0.f;
}

// ---- kernel 3: fused GEMM: out = X@W[e]  +  V' @ B2[e]   (K = 1024 + 64) ----
// 128x128 tile, BK=32, 4 waves (each 64x64 via 4x4 frags of 16x16x32 MFMA).
// fp32 global -> cvt bf16 -> LDS.  As: [128][32] row-major (k-contig).
// Bs: oct-interleaved [k/8][n][8] so B-frag = one ds_read_b128.
__global__ __launch_bounds__(256) void k_gemm_fused(
    const float* __restrict__ x, const float* __restrict__ weight,
    const float* __restrict__ lora_B, const float* __restrict__ vprime,
    const int* __restrict__ tok_exp, float* __restrict__ out) {
  __shared__ ushort As[128 * 32];      // 8 KB
  __shared__ ushort Bs[4 * 128 * 8];   // 8 KB

  const int tid = threadIdx.x;
  const int lane = tid & 63;
  const int wave = tid >> 6;
  const int wm = wave >> 1, wn = wave & 1;

  const int ntile = blockIdx.x;        // 0..7
  const int mtile = blockIdx.y;        // 0..63
  const int row0 = mtile * 128;
  const int n0 = ntile * 128;
  const int e = tok_exp[row0];

  const float* wbase = weight + (size_t)e * DIN * DOUT;

  f32x4 acc[4][4];
#pragma unroll
  for (int mi = 0; mi < 4; ++mi)
#pragma unroll
    for (int ni = 0; ni < 4; ++ni) acc[mi][ni] = (f32x4){0.f, 0.f, 0.f, 0.f};

  const int ko = wave;                 // k-oct id for B staging (0..3)
  const int p = lane;                  // n-pair id (0..63)

  for (int kt = 0; kt < 34; ++kt) {
    // ---- stage A: 128 rows x 32 k, fp32 -> bf16 ----
    {
      const float* abase; int astride;
      if (kt < 32) { abase = x + (size_t)row0 * DIN + kt * 32; astride = DIN; }
      else         { abase = vprime + (size_t)row0 * 64 + (kt - 32) * 32; astride = 64; }
#pragma unroll
      for (int q = 0; q < 4; ++q) {
        int chunk = tid + q * 256;     // 0..1023 ; coalesced across tid
        int row = chunk >> 3, c4 = chunk & 7;
        float4 v = *(const float4*)(abase + (size_t)row * astride + c4 * 4);
        ushort4 b;
        b.x = f2bf(v.x); b.y = f2bf(v.y); b.z = f2bf(v.z); b.w = f2bf(v.w);
        *(ushort4*)&As[row * 32 + c4 * 4] = b;
      }
    }
    // ---- stage B: 32 k x 128 n, fp32 -> bf16, oct-interleave ----
    {
      float2 d[8];
      if (kt < 32) {
        const float* bb = wbase + (size_t)(kt * 32 + ko * 8) * DOUT + n0 + 2 * p;
#pragma unroll
        for (int j = 0; j < 8; ++j) d[j] = *(const float2*)(bb + (size_t)j * DOUT);
      } else {
#pragma unroll
        for (int j = 0; j < 8; ++j) {
          int kv = (kt - 32) * 32 + ko * 8 + j;   // virtual LoRA k in [0,64)
          int a = kv >> 4, r = kv & 15;
          d[j] = *(const float2*)(lora_B + (size_t)((a * NE + e) * RK + r) * DOUT + n0 + 2 * p);
        }
      }
      uint32_t lo[4], hi[4];
#pragma unroll
      for (int j = 0; j < 4; ++j) {
        lo[j] = (uint32_t)f2bf(d[2 * j].x) | ((uint32_t)f2bf(d[2 * j + 1].x) << 16);
        hi[j] = (uint32_t)f2bf(d[2 * j].y) | ((uint32_t)f2bf(d[2 * j + 1].y) << 16);
      }
      *(uint4*)&Bs[ko * 1024 + p * 16]     = make_uint4(lo[0], lo[1], lo[2], lo[3]);
      *(uint4*)&Bs[ko * 1024 + p * 16 + 8] = make_uint4(hi[0], hi[1], hi[2], hi[3]);
    }
    __syncthreads();

    // ---- compute: 16 MFMAs per wave ----
    short8 af[4], bfv[4];
#pragma unroll
    for (int mi = 0; mi < 4; ++mi) {
      int m = wm * 64 + mi * 16 + (lane & 15);
      af[mi] = *(const short8*)&As[m * 32 + (lane >> 4) * 8];
    }
#pragma unroll
    for (int ni = 0; ni < 4; ++ni) {
      int n = wn * 64 + ni * 16 + (lane & 15);
      bfv[ni] = *(const short8*)&Bs[((lane >> 4) * 128 + n) * 8];
    }
#pragma unroll
    for (int mi = 0; mi < 4; ++mi)
#pragma unroll
      for (int ni = 0; ni < 4; ++ni)
        acc[mi][ni] = __builtin_amdgcn_mfma_f32_16x16x32_bf16(
            af[mi], bfv[ni], acc[mi][ni], 0, 0, 0);
    __syncthreads();
  }

  // ---- epilogue: C layout col=lane&15, row=(lane>>4)*4+reg ; fp32 out ----
#pragma unroll
  for (int mi = 0; mi < 4; ++mi) {
#pragma unroll
    for (int ni = 0; ni < 4; ++ni) {
      int col = n0 + wn * 64 + ni * 16 + (lane & 15);
#pragma unroll
      for (int i = 0; i < 4; ++i) {
        int row = row0 + wm * 64 + mi * 16 + (lane >> 4) * 4 + i;
        out[(size_t)row * DOUT + col] = acc[mi][ni][i];
      }
    }
  }
}

extern "C" void kernel_launch(void* const* d_in, const int* in_sizes, int n_in,
                              void* d_out, int out_size, void* d_ws, size_t ws_size,
                              hipStream_t stream) {
  const float* x            = (const float*)d_in[0];
  const float* weight       = (const float*)d_in[1];
  const float* lora_A       = (const float*)d_in[2];
  const float* lora_B       = (const float*)d_in[3];
  const float* lora_scaling = (const float*)d_in[4];
  const int*   group_sizes  = (const int*)d_in[5];
  const int*   adapter_idx  = (const int*)d_in[6];
  float* out = (float*)d_out;

  int*   tok_exp = (int*)d_ws;                                    // 32 KB
  float* vprime  = (float*)((char*)d_ws + T_TOK * sizeof(int));   // 2 MB

  k_token_expert<<<T_TOK / 256, 256, 0, stream>>>(group_sizes, tok_exp);
  k_vprime<<<T_TOK / 4, 256, 0, stream>>>(x, lora_A, lora_scaling, adapter_idx,
                                          tok_exp, vprime);
  dim3 grid(DOUT / 128, T_TOK / 128);
  k_gemm_fused<<<grid, 256, 0, stream>>>(x, weight, lora_B, vprime, tok_exp, out);
}